// Round 9
// baseline (208.586 us; speedup 1.0000x reference)
//
#include <hip/hip_runtime.h>
#include <hip/hip_bf16.h>
#include <math.h>

// Problem constants (fixed by the reference)
#define BB 32
#define LL 768
#define DD 256
#define FF 256
#define TT 3072
#define MT 48              // dp output rows per block -> grid 512 = 2 blocks/CU.
                           // R2-R8: MT=24 (R3), 8-wave (R4), nt=16 (R6), gather-merge
                           // (R8) all regressed. This geometry is the local optimum.
#define PAD 262            // LDS row stride (bf16): dword stride 131 == 3 (mod 32)

typedef __attribute__((ext_vector_type(8))) short bf16x8;
typedef __attribute__((ext_vector_type(4))) float f32x4;

__device__ inline unsigned short f2b(float f) {
    union { float f; unsigned u; } v; v.f = f;
    unsigned r = (v.u + 0x7FFF + ((v.u >> 16) & 1)) >> 16;  // RNE
    return (unsigned short)r;
}

// packed f32x2 -> bf16x2 (RNE), single VALU op
__device__ inline unsigned cvt_pk_bf16(float lo, float hi) {
    unsigned r;
    asm("v_cvt_pk_bf16_f32 %0, %1, %2" : "=v"(r) : "v"(lo), "v"(hi));
    return r;
}

// ---------------------------------------------------------------------------
// 16-lane-group sum via DPP row rotations (verified R2: bank conflicts = 0).
// ---------------------------------------------------------------------------
#define DPP_ROR_ADD(v, ctrl)                                                   \
    v += __int_as_float(__builtin_amdgcn_update_dpp(                           \
        0, __float_as_int(v), ctrl, 0xF, 0xF, false))

__device__ inline void red16_pair(float& a, float& b) {
    DPP_ROR_ADD(a, 0x128); DPP_ROR_ADD(b, 0x128);   // ror:8
    DPP_ROR_ADD(a, 0x124); DPP_ROR_ADD(b, 0x124);   // ror:4
    DPP_ROR_ADD(a, 0x122); DPP_ROR_ADD(b, 0x122);   // ror:2
    DPP_ROR_ADD(a, 0x121); DPP_ROR_ADD(b, 0x121);   // ror:1
}

__device__ inline float red16_one(float a) {
    DPP_ROR_ADD(a, 0x128);
    DPP_ROR_ADD(a, 0x124);
    DPP_ROR_ADD(a, 0x122);
    DPP_ROR_ADD(a, 0x121);
    return a;
}

// ---------------------------------------------------------------------------
// MERGED: weight prep (blocks 0..47) + scan/dpo/idx_map (blocks 48..79).
//   wQ[s*8192 + n*32 + q*8 + j] = bf16(w[kc][c8*32+q*8+j][n]),  s = kc*8+c8
// ---------------------------------------------------------------------------
__global__ __launch_bounds__(256) void prep_scan_kernel(
    const float* __restrict__ w1, const float* __restrict__ w2,
    unsigned short* __restrict__ wQ1, unsigned short* __restrict__ wQ2,
    const int* __restrict__ target,    // [B, L]
    float* __restrict__ out_dpo,       // [B, L] (stored as float)
    int* __restrict__ idx_map)         // [B, T]
{
    __shared__ int tsum[256];
    const int tid = threadIdx.x;

    if (blockIdx.x < 48) {
        // ---------------- weight prep ----------------
        const int layer = blockIdx.x / 24;
        const int s  = blockIdx.x % 24;
        const int kc = s >> 3, c8 = s & 7;
        const float* __restrict__ w = layer ? w2 : w1;
        unsigned short* __restrict__ o = (layer ? wQ2 : wQ1) + s * 8192 + tid * 32;
        const int n = tid;

        alignas(16) unsigned short tmp[32];
#pragma unroll
        for (int q = 0; q < 4; ++q)
#pragma unroll
            for (int j = 0; j < 8; ++j) {
                const int cin = c8 * 32 + q * 8 + j;
                tmp[q * 8 + j] = f2b(w[((size_t)(kc * 256 + cin)) * 256 + n]);
            }
#pragma unroll
        for (int i = 0; i < 4; ++i)
            *reinterpret_cast<uint4*>(o + i * 8) = *reinterpret_cast<const uint4*>(tmp + i * 8);
        return;
    }

    // ---------------- scan: dpo + cumsum + scatter idx map ----------------
    const int b = blockIdx.x - 48;

    const int l = 3 * tid;
    const int v0 = target[b * LL + l];
    const int v1 = target[b * LL + l + 1];
    const int v2 = target[b * LL + l + 2];
    out_dpo[b * LL + l]     = (float)v0;
    out_dpo[b * LL + l + 1] = (float)v1;
    out_dpo[b * LL + l + 2] = (float)v2;

    const int s0 = v0, s1 = v0 + v1, s2 = v0 + v1 + v2;
    tsum[tid] = s2;
    __syncthreads();
    for (int off = 1; off < 256; off <<= 1) {
        int xq = (tid >= off) ? tsum[tid - off] : 0;
        __syncthreads();
        tsum[tid] += xq;
        __syncthreads();
    }
    const int excl = tsum[tid] - s2;

    for (int t = tid; t < TT; t += 256) idx_map[b * TT + t] = -1;
    __syncthreads();

    const int c0 = excl + s0, c1 = excl + s1, c2 = excl + s2;
    for (int t = excl; t < c0 && t < TT; ++t) idx_map[b * TT + t] = l;
    for (int t = c0;   t < c1 && t < TT; ++t) idx_map[b * TT + t] = l + 1;
    for (int t = c1;   t < c2 && t < TT; ++t) idx_map[b * TT + t] = l + 2;
}

// ---------------------------------------------------------------------------
// FUSED DurationPredictor — R9: conv1 A-fragments loaded IN-REGISTER straight
// from global x (L2/L3-hot, rows identical across waves) with a two-deep
// issue->MFMA->convert pipeline.  Deletes the whole LDS stage phase, the
// zero-fill, and 3 barriers (9 -> 6).  conv2 keeps h2 in LDS (cross-wave
// rows) with first b-fragments prefetched under the h2-ready barrier.
// ---------------------------------------------------------------------------
__global__ __launch_bounds__(256, 2) void fused_dp_kernel(
    const float* __restrict__ x,               // [B, L, 256] fp32
    const unsigned short* __restrict__ wQ1,    // fragment-major conv1 weights
    const unsigned short* __restrict__ wQ2,    // fragment-major conv2 weights
    const float* __restrict__ c1b, const float* __restrict__ g1, const float* __restrict__ b1,
    const float* __restrict__ c2b, const float* __restrict__ g2, const float* __restrict__ b2,
    const float* __restrict__ lw,  const float* __restrict__ lb,
    float* __restrict__ out_dur)               // [B, L]
{
    __shared__ unsigned short h2[50 * PAD];    // 26.2 KB LN'd conv1 rows (bf16)
    __shared__ float red[4][4][4][4][2];       // [wave][mt][quad][r][{s1,s2}]
    __shared__ float redp[4][3][4][4];         // [wave][mt2][quad][r] head partials
    __shared__ float fin[50][2];               // per-row (mu, rstd)

    const int tid  = threadIdx.x;
    const int b    = blockIdx.x / (LL / MT);
    const int l0   = (blockIdx.x % (LL / MT)) * MT;
    const int wave = tid >> 6, lane = tid & 63;
    const int quad = lane >> 4, l16 = lane & 15;

    // ---- hoist per-lane column constants ----
    int   cols[4];
    float c1bv[4], g1v[4], b1v[4], c2bv[4], g2v[4], b2v[4], lwv[4];
#pragma unroll
    for (int nt = 0; nt < 4; ++nt) {
        const int c = wave * 64 + nt * 16 + l16;
        cols[nt] = c;
        c1bv[nt] = c1b[c]; g1v[nt] = g1[c]; b1v[nt] = b1[c];
        c2bv[nt] = c2b[c]; g2v[nt] = g2[c]; b2v[nt] = b2[c];
        lwv[nt]  = lw[c];
    }
    const float lbv = lb[0];

    // ---- conv1 K-loop: A-frags in-register from global x, 2-deep pipeline ----
    // a[mt][j] = bf16(x[l0-2 + 16mt+l16+kc][c8*32+quad*8+j]); rows with
    // ar>=52 or l outside [0,LL) contribute zeros (matches old A1 semantics).
    f32x4 acc1[4][4] = {};
    {
        bf16x8 aE[4], bE[4], aO[4], bO[4];
        float4 r0[4], r1[4];                   // raw f32 staging (1 step in flight)
        auto issue1 = [&](bf16x8* bf, int s) {
            const int kc = s >> 3, c8 = s & 7;
#pragma unroll
            for (int mt = 0; mt < 4; ++mt) {
                const int ar = 16 * mt + l16 + kc;
                const int l  = l0 - 2 + ar;
                float4 z = {0.f, 0.f, 0.f, 0.f};
                r0[mt] = z; r1[mt] = z;
                if (ar < 52 && l >= 0 && l < LL) {
                    const float* pp = x + ((size_t)b * LL + l) * DD + c8 * 32 + quad * 8;
                    r0[mt] = *reinterpret_cast<const float4*>(pp);
                    r1[mt] = *reinterpret_cast<const float4*>(pp + 4);
                }
            }
#pragma unroll
            for (int nt = 0; nt < 4; ++nt)
                bf[nt] = *reinterpret_cast<const bf16x8*>(
                    wQ1 + (size_t)s * 8192 + cols[nt] * 32 + quad * 8);
        };
        auto cvt1 = [&](bf16x8* a) {
#pragma unroll
            for (int mt = 0; mt < 4; ++mt) {
                union { unsigned u[4]; bf16x8 v; } t;
                t.u[0] = cvt_pk_bf16(r0[mt].x, r0[mt].y);
                t.u[1] = cvt_pk_bf16(r0[mt].z, r0[mt].w);
                t.u[2] = cvt_pk_bf16(r1[mt].x, r1[mt].y);
                t.u[3] = cvt_pk_bf16(r1[mt].z, r1[mt].w);
                a[mt] = t.v;
            }
        };
        auto mm1 = [&](bf16x8* a, bf16x8* bf) {
            __builtin_amdgcn_s_setprio(1);
#pragma unroll
            for (int mt = 0; mt < 4; ++mt)
#pragma unroll
                for (int nt = 0; nt < 4; ++nt)
                    acc1[mt][nt] = __builtin_amdgcn_mfma_f32_16x16x32_bf16(
                        a[mt], bf[nt], acc1[mt][nt], 0, 0, 0);
            __builtin_amdgcn_s_setprio(0);
        };
        issue1(bE, 0);
        cvt1(aE);                              // step 0 ready (one exposed latency)
        for (int s = 0; s < 24; s += 2) {
            issue1(bO, s + 1);                 // s+1 raw loads in flight
            mm1(aE, bE);                       // compute s (covers latency)
            cvt1(aO);                          // materialize s+1
            if (s + 2 < 24) issue1(bE, s + 2); // s+2 in flight
            mm1(aO, bO);                       // compute s+1
            if (s + 2 < 24) cvt1(aE);          // materialize s+2
        }
    }

    // ---- LN1 stats: register-direct quad-group DPP reduction ----
#pragma unroll
    for (int mt = 0; mt < 4; ++mt)
#pragma unroll
        for (int r = 0; r < 4; ++r) {
            float s1 = 0.f, s2 = 0.f;
#pragma unroll
            for (int nt = 0; nt < 4; ++nt) {
                const float v = fmaxf(acc1[mt][nt][r] + c1bv[nt], 0.f);
                s1 += v; s2 += v * v;
            }
            red16_pair(s1, s2);
            if (l16 == 0) { red[wave][mt][quad][r][0] = s1; red[wave][mt][quad][r][1] = s2; }
        }
    __syncthreads();
    if (tid < 50) {
        const int mt = tid >> 4, q = (tid >> 2) & 3, r = tid & 3;
        const float s1 = red[0][mt][q][r][0] + red[1][mt][q][r][0]
                       + red[2][mt][q][r][0] + red[3][mt][q][r][0];
        const float s2 = red[0][mt][q][r][1] + red[1][mt][q][r][1]
                       + red[2][mt][q][r][1] + red[3][mt][q][r][1];
        const float mu  = s1 * (1.f / 256.f);
        const float var = s2 * (1.f / 256.f) - mu * mu;
        fin[tid][0] = mu;
        fin[tid][1] = rsqrtf(var + 1e-5f);
    }
    __syncthreads();

    // ---- write h2 = LN1 rows (h rows l0-1..l0+48; zero outside sequence) ----
#pragma unroll
    for (int mt = 0; mt < 4; ++mt)
#pragma unroll
        for (int r = 0; r < 4; ++r) {
            const int rho = 16 * mt + quad * 4 + r;
            if (rho < 50) {
                const int gr = l0 - 1 + rho;          // global h row
                const float mu = fin[rho][0], rstd = fin[rho][1];
#pragma unroll
                for (int nt = 0; nt < 4; ++nt) {
                    unsigned short hv = 0;
                    if (gr >= 0 && gr < LL) {
                        const float v = fmaxf(acc1[mt][nt][r] + c1bv[nt], 0.f);
                        hv = f2b((v - mu) * rstd * g1v[nt] + b1v[nt]);
                    }
                    h2[rho * PAD + cols[nt]] = hv;
                }
            }
        }

    // ---- conv2: prefetch first b-fragments UNDER the h2-ready barrier ----
    bf16x8 aE2[3], bE2[4], aO2[3], bO2[4];
    auto ldb2 = [&](bf16x8* bf, int s) {
#pragma unroll
        for (int nt = 0; nt < 4; ++nt)
            bf[nt] = *reinterpret_cast<const bf16x8*>(
                wQ2 + (size_t)s * 8192 + cols[nt] * 32 + quad * 8);
    };
    auto lda2 = [&](bf16x8* a, int s) {
        const int kc = s >> 3, c8 = s & 7;
#pragma unroll
        for (int mt = 0; mt < 3; ++mt)
            a[mt] = *reinterpret_cast<const bf16x8*>(
                &h2[(16 * mt + l16 + kc) * PAD + c8 * 32 + quad * 8]);
    };
    ldb2(bE2, 0);
    ldb2(bO2, 1);
    __syncthreads();   // h2 ready (b loads of steps 0/1 hide under the barrier)

    // ---- conv2 K-loop: 3 m-tiles, two-deep double-buffered fragments ----
    f32x4 acc2[3][4] = {};
    {
        auto mm2 = [&](bf16x8* a, bf16x8* bf) {
            __builtin_amdgcn_s_setprio(1);
#pragma unroll
            for (int mt = 0; mt < 3; ++mt)
#pragma unroll
                for (int nt = 0; nt < 4; ++nt)
                    acc2[mt][nt] = __builtin_amdgcn_mfma_f32_16x16x32_bf16(
                        a[mt], bf[nt], acc2[mt][nt], 0, 0, 0);
            __builtin_amdgcn_s_setprio(0);
        };
        lda2(aE2, 0);
        for (int s = 0; s < 24; s += 2) {
            lda2(aO2, s + 1);
            mm2(aE2, bE2);
            if (s + 2 < 24) { ldb2(bE2, s + 2); lda2(aE2, s + 2); }
            mm2(aO2, bO2);
            if (s + 3 < 24) ldb2(bO2, s + 3);
        }
    }

    // ---- LN2 stats ----
#pragma unroll
    for (int mt = 0; mt < 3; ++mt)
#pragma unroll
        for (int r = 0; r < 4; ++r) {
            float s1 = 0.f, s2 = 0.f;
#pragma unroll
            for (int nt = 0; nt < 4; ++nt) {
                const float v = fmaxf(acc2[mt][nt][r] + c2bv[nt], 0.f);
                s1 += v; s2 += v * v;
            }
            red16_pair(s1, s2);
            if (l16 == 0) { red[wave][mt][quad][r][0] = s1; red[wave][mt][quad][r][1] = s2; }
        }
    __syncthreads();
    if (tid < MT) {
        const int mt = tid >> 4, q = (tid >> 2) & 3, r = tid & 3;
        const float s1 = red[0][mt][q][r][0] + red[1][mt][q][r][0]
                       + red[2][mt][q][r][0] + red[3][mt][q][r][0];
        const float s2 = red[0][mt][q][r][1] + red[1][mt][q][r][1]
                       + red[2][mt][q][r][1] + red[3][mt][q][r][1];
        const float mu  = s1 * (1.f / 256.f);
        const float var = s2 * (1.f / 256.f) - mu * mu;
        fin[tid][0] = mu;
        fin[tid][1] = rsqrtf(var + 1e-5f);
    }
    __syncthreads();

    // ---- head: dp = sum_col LN2(v)*lw  (direct reference formula) ----
#pragma unroll
    for (int mt = 0; mt < 3; ++mt)
#pragma unroll
        for (int r = 0; r < 4; ++r) {
            const int rho = 16 * mt + quad * 4 + r;
            const float mu = fin[rho][0], rstd = fin[rho][1];
            float p = 0.f;
#pragma unroll
            for (int nt = 0; nt < 4; ++nt) {
                const float v = fmaxf(acc2[mt][nt][r] + c2bv[nt], 0.f);
                p += ((v - mu) * rstd * g2v[nt] + b2v[nt]) * lwv[nt];
            }
            p = red16_one(p);
            if (l16 == 0) redp[wave][mt][quad][r] = p;
        }
    __syncthreads();
    if (tid < MT) {
        const int mt = tid >> 4, q = (tid >> 2) & 3, r = tid & 3;
        const float dp = redp[0][mt][q][r] + redp[1][mt][q][r]
                       + redp[2][mt][q][r] + redp[3][mt][q][r] + lbv;
        out_dur[(size_t)b * LL + l0 + tid] = expf(dp);
    }
}

// ---------------------------------------------------------------------------
// Gather: out[b,t,:] = x[b, idx_map[b][t], :]  (zeros when masked)
// Streaming output (100.7 MB, no reuse) -> nontemporal stores via ext-vector
// f32x4 (native clang vector type).
// ---------------------------------------------------------------------------
__global__ __launch_bounds__(256) void gather_kernel(
    const float* __restrict__ x,       // [B, L, 256]
    const int* __restrict__ idx_map,   // [B, T]
    float* __restrict__ out)           // [B, T, 256]
{
    const int wv = threadIdx.x >> 6, lane = threadIdx.x & 63;
    const int row = blockIdx.x * 4 + wv;          // row in [0, B*T)
    const int b = row / TT, t = row - b * TT;
    const int idx = idx_map[b * TT + t];
    f32x4 val = {0.f, 0.f, 0.f, 0.f};
    if (idx >= 0)
        val = *reinterpret_cast<const f32x4*>(x + ((size_t)(b * LL + idx)) * DD + lane * 4);
    __builtin_nontemporal_store(val, reinterpret_cast<f32x4*>(out) + (size_t)row * (DD / 4) + lane);
}

// ---------------------------------------------------------------------------
extern "C" void kernel_launch(void* const* d_in, const int* in_sizes, int n_in,
                              void* d_out, int out_size, void* d_ws, size_t ws_size,
                              hipStream_t stream)
{
    const float* x      = (const float*)d_in[0];
    const int*   target = (const int*)  d_in[1];
    const float* c1w = (const float*)d_in[3];
    const float* c1b = (const float*)d_in[4];
    const float* g1  = (const float*)d_in[5];
    const float* b1  = (const float*)d_in[6];
    const float* c2w = (const float*)d_in[7];
    const float* c2b = (const float*)d_in[8];
    const float* g2  = (const float*)d_in[9];
    const float* b2  = (const float*)d_in[10];
    const float* lw  = (const float*)d_in[11];
    const float* lb  = (const float*)d_in[12];

    float* out0    = (float*)d_out;                       // [B, T, 256]
    float* out_dpo = out0 + (size_t)BB * TT * DD;         // [B, L]
    float* out_dur = out_dpo + (size_t)BB * LL;           // [B, L]

    // workspace layout
    char* ws = (char*)d_ws;
    unsigned short* wQ1 = (unsigned short*)ws;                 ws += (size_t)24 * 8192 * 2;
    unsigned short* wQ2 = (unsigned short*)ws;                 ws += (size_t)24 * 8192 * 2;
    int* idx_map        = (int*)ws;

    prep_scan_kernel<<<48 + BB, 256, 0, stream>>>(
        c1w, c2w, wQ1, wQ2, target, out_dpo, idx_map);

    fused_dp_kernel<<<BB * (LL / MT), 256, 0, stream>>>(
        x, wQ1, wQ2, c1b, g1, b1, c2b, g2, b2, lw, lb, out_dur);

    gather_kernel<<<BB * TT / 4, 256, 0, stream>>>(x, idx_map, out0);
}

// Round 10
// 193.388 us; speedup vs baseline: 1.0786x; 1.0786x over previous
//
#include <hip/hip_runtime.h>
#include <hip/hip_bf16.h>
#include <math.h>

// Problem constants (fixed by the reference)
#define BB 32
#define LL 768
#define DD 256
#define FF 256
#define TT 3072
#define MT 48              // dp output rows per block -> grid 512 = 2 blocks/CU.
                           // R2-R9: MT=24 (R3), 8-wave (R4), nt=16 (R6), gather-merge
                           // (R8), reg-direct conv1 (R9) all regressed. Local optimum.
#define PAD 262            // LDS row stride (bf16): dword stride 131 == 3 (mod 32)
#define A1R 66             // A1 rows (memory-safe read range 0..65; rows >=52 zeroed)

typedef __attribute__((ext_vector_type(8))) short bf16x8;
typedef __attribute__((ext_vector_type(4))) float f32x4;

__device__ inline unsigned short f2b(float f) {
    union { float f; unsigned u; } v; v.f = f;
    unsigned r = (v.u + 0x7FFF + ((v.u >> 16) & 1)) >> 16;  // RNE
    return (unsigned short)r;
}

// packed f32x2 -> bf16x2 (RNE), single VALU op
__device__ inline unsigned cvt_pk_bf16(float lo, float hi) {
    unsigned r;
    asm("v_cvt_pk_bf16_f32 %0, %1, %2" : "=v"(r) : "v"(lo), "v"(hi));
    return r;
}

// ---------------------------------------------------------------------------
// 16-lane-group sum via DPP row rotations (verified R2: bank conflicts = 0).
// ---------------------------------------------------------------------------
#define DPP_ROR_ADD(v, ctrl)                                                   \
    v += __int_as_float(__builtin_amdgcn_update_dpp(                           \
        0, __float_as_int(v), ctrl, 0xF, 0xF, false))

__device__ inline void red16_pair(float& a, float& b) {
    DPP_ROR_ADD(a, 0x128); DPP_ROR_ADD(b, 0x128);   // ror:8
    DPP_ROR_ADD(a, 0x124); DPP_ROR_ADD(b, 0x124);   // ror:4
    DPP_ROR_ADD(a, 0x122); DPP_ROR_ADD(b, 0x122);   // ror:2
    DPP_ROR_ADD(a, 0x121); DPP_ROR_ADD(b, 0x121);   // ror:1
}

__device__ inline float red16_one(float a) {
    DPP_ROR_ADD(a, 0x128);
    DPP_ROR_ADD(a, 0x124);
    DPP_ROR_ADD(a, 0x122);
    DPP_ROR_ADD(a, 0x121);
    return a;
}

// ---------------------------------------------------------------------------
// MERGED: weight prep (blocks 0..47) + scan/dpo/idx_map (blocks 48..79).
//   wQ[s*8192 + n*32 + q*8 + j] = bf16(w[kc][c8*32+q*8+j][n]),  s = kc*8+c8
// ---------------------------------------------------------------------------
__global__ __launch_bounds__(256) void prep_scan_kernel(
    const float* __restrict__ w1, const float* __restrict__ w2,
    unsigned short* __restrict__ wQ1, unsigned short* __restrict__ wQ2,
    const int* __restrict__ target,    // [B, L]
    float* __restrict__ out_dpo,       // [B, L] (stored as float)
    int* __restrict__ idx_map)         // [B, T]
{
    __shared__ int tsum[256];
    const int tid = threadIdx.x;

    if (blockIdx.x < 48) {
        // ---------------- weight prep ----------------
        const int layer = blockIdx.x / 24;
        const int s  = blockIdx.x % 24;
        const int kc = s >> 3, c8 = s & 7;
        const float* __restrict__ w = layer ? w2 : w1;
        unsigned short* __restrict__ o = (layer ? wQ2 : wQ1) + s * 8192 + tid * 32;
        const int n = tid;

        alignas(16) unsigned short tmp[32];
#pragma unroll
        for (int q = 0; q < 4; ++q)
#pragma unroll
            for (int j = 0; j < 8; ++j) {
                const int cin = c8 * 32 + q * 8 + j;
                tmp[q * 8 + j] = f2b(w[((size_t)(kc * 256 + cin)) * 256 + n]);
            }
#pragma unroll
        for (int i = 0; i < 4; ++i)
            *reinterpret_cast<uint4*>(o + i * 8) = *reinterpret_cast<const uint4*>(tmp + i * 8);
        return;
    }

    // ---------------- scan: dpo + cumsum + scatter idx map ----------------
    const int b = blockIdx.x - 48;

    const int l = 3 * tid;
    const int v0 = target[b * LL + l];
    const int v1 = target[b * LL + l + 1];
    const int v2 = target[b * LL + l + 2];
    out_dpo[b * LL + l]     = (float)v0;
    out_dpo[b * LL + l + 1] = (float)v1;
    out_dpo[b * LL + l + 2] = (float)v2;

    const int s0 = v0, s1 = v0 + v1, s2 = v0 + v1 + v2;
    tsum[tid] = s2;
    __syncthreads();
    for (int off = 1; off < 256; off <<= 1) {
        int xq = (tid >= off) ? tsum[tid - off] : 0;
        __syncthreads();
        tsum[tid] += xq;
        __syncthreads();
    }
    const int excl = tsum[tid] - s2;

    for (int t = tid; t < TT; t += 256) idx_map[b * TT + t] = -1;
    __syncthreads();

    const int c0 = excl + s0, c1 = excl + s1, c2 = excl + s2;
    for (int t = excl; t < c0 && t < TT; ++t) idx_map[b * TT + t] = l;
    for (int t = c0;   t < c1 && t < TT; ++t) idx_map[b * TT + t] = l + 1;
    for (int t = c1;   t < c2 && t < TT; ++t) idx_map[b * TT + t] = l + 2;
}

// ---------------------------------------------------------------------------
// FUSED DurationPredictor — R7 structure (best: 193.3 total) + R10 pipeline
// deepening:
//  * b-fragment ring buffer, 4 deep: b issued 2 K-steps ahead (L2 latency
//    ~200-400cyc > 1-step MFMA cover of ~154cyc; 2-ahead covers it)
//  * first two b-loads of each conv hoisted ABOVE the preceding barrier --
//    the barrier's vmcnt drain completes them for free
//  * a-fragments stay 2-deep from LDS (~120cyc, covered by 1 step)
// ---------------------------------------------------------------------------
__global__ __launch_bounds__(256, 2) void fused_dp_kernel(
    const float* __restrict__ x,               // [B, L, 256] fp32
    const unsigned short* __restrict__ wQ1,    // fragment-major conv1 weights
    const unsigned short* __restrict__ wQ2,    // fragment-major conv2 weights
    const float* __restrict__ c1b, const float* __restrict__ g1, const float* __restrict__ b1,
    const float* __restrict__ c2b, const float* __restrict__ g2, const float* __restrict__ b2,
    const float* __restrict__ lw,  const float* __restrict__ lb,
    float* __restrict__ out_dur)               // [B, L]
{
    __shared__ union {
        unsigned short A1[A1R * PAD];          // 34.6 KB staged x rows (bf16)
        unsigned short h2[50 * PAD];           // 26.2 KB LN'd conv1 rows (bf16)
    } sm;
    __shared__ float red[4][4][4][4][2];       // [wave][mt][quad][r][{s1,s2}]
    __shared__ float redp[4][3][4][4];         // [wave][mt2][quad][r] head partials
    __shared__ float fin[50][2];               // per-row (mu, rstd)

    const int tid  = threadIdx.x;
    const int b    = blockIdx.x / (LL / MT);
    const int l0   = (blockIdx.x % (LL / MT)) * MT;
    const int wave = tid >> 6, lane = tid & 63;
    const int quad = lane >> 4, l16 = lane & 15;

    // ---- hoist per-lane column constants ----
    int   cols[4];
    float c1bv[4], g1v[4], b1v[4], c2bv[4], g2v[4], b2v[4], lwv[4];
#pragma unroll
    for (int nt = 0; nt < 4; ++nt) {
        const int c = wave * 64 + nt * 16 + l16;
        cols[nt] = c;
        c1bv[nt] = c1b[c]; g1v[nt] = g1[c]; b1v[nt] = b1[c];
        c2bv[nt] = c2b[c]; g2v[nt] = g2[c]; b2v[nt] = b2[c];
        lwv[nt]  = lw[c];
    }
    const float lbv = lb[0];

    // ---- stage x rows l0-2 .. l0+49 (rows 52..65 zeroed), BATCHED loads ----
    {
        float4 v0[7], v1[7];
        int lr[7];
#pragma unroll
        for (int k = 0; k < 7; ++k) {
            const int q  = tid + (k << 8);
            const int ar = q >> 5;
            const int l  = l0 - 2 + ar;
            lr[k] = (ar < 52 && l >= 0 && l < LL) ? l : -1;
            if (lr[k] >= 0) {
                const float* pp = x + ((size_t)b * LL + lr[k]) * DD + (q & 31) * 8;
                v0[k] = *reinterpret_cast<const float4*>(pp);
                v1[k] = *reinterpret_cast<const float4*>(pp + 4);
            }
        }
#pragma unroll
        for (int k = 0; k < 7; ++k) {
            const int q  = tid + (k << 8);
            const int ar = q >> 5;
            uint4 uu = {0u, 0u, 0u, 0u};
            if (lr[k] >= 0) {
                uu.x = cvt_pk_bf16(v0[k].x, v0[k].y);
                uu.y = cvt_pk_bf16(v0[k].z, v0[k].w);
                uu.z = cvt_pk_bf16(v1[k].x, v1[k].y);
                uu.w = cvt_pk_bf16(v1[k].z, v1[k].w);
            }
            *reinterpret_cast<uint4*>(&sm.A1[ar * PAD + (q & 31) * 8]) = uu;
        }
        for (int q = tid; q < 320; q += 256) {
            const int ar = 56 + (q >> 5);
            uint4 z = {0u, 0u, 0u, 0u};
            *reinterpret_cast<uint4*>(&sm.A1[ar * PAD + (q & 31) * 8]) = z;
        }
    }

    // ---- conv1: b ring (4 deep), a dbuf (2 deep) ----
    f32x4 acc1[4][4] = {};
    {
        bf16x8 br[4][4], ar2[2][4];
        auto ldb1 = [&](int buf, int s) {
#pragma unroll
            for (int nt = 0; nt < 4; ++nt)
                br[buf][nt] = *reinterpret_cast<const bf16x8*>(
                    wQ1 + (size_t)s * 8192 + cols[nt] * 32 + quad * 8);
        };
        auto lda1 = [&](int buf, int s) {
            const int kc = s >> 3, c8 = s & 7;
#pragma unroll
            for (int mt = 0; mt < 4; ++mt)
                ar2[buf][mt] = *reinterpret_cast<const bf16x8*>(
                    &sm.A1[(16 * mt + l16 + kc) * PAD + c8 * 32 + quad * 8]);
        };
        auto mm1 = [&](int ab, int bb) {
            __builtin_amdgcn_s_setprio(1);
#pragma unroll
            for (int mt = 0; mt < 4; ++mt)
#pragma unroll
                for (int nt = 0; nt < 4; ++nt)
                    acc1[mt][nt] = __builtin_amdgcn_mfma_f32_16x16x32_bf16(
                        ar2[ab][mt], br[bb][nt], acc1[mt][nt], 0, 0, 0);
            __builtin_amdgcn_s_setprio(0);
        };
        // b steps 0,1 issued pre-barrier: barrier's vmcnt drain retires them free
        ldb1(0, 0);
        ldb1(1, 1);
        __syncthreads();   // A1 ready
        lda1(0, 0);
#pragma unroll
        for (int s = 0; s < 24; ++s) {
            if (s + 2 < 24) ldb1((s + 2) & 3, s + 2);   // b 2 ahead
            if (s + 1 < 24) lda1((s + 1) & 1, s + 1);   // a 1 ahead
            mm1(s & 1, s & 3);
        }
    }
    __syncthreads();   // A1 dead

    // ---- LN1 stats: register-direct quad-group DPP reduction ----
#pragma unroll
    for (int mt = 0; mt < 4; ++mt)
#pragma unroll
        for (int r = 0; r < 4; ++r) {
            float s1 = 0.f, s2 = 0.f;
#pragma unroll
            for (int nt = 0; nt < 4; ++nt) {
                const float v = fmaxf(acc1[mt][nt][r] + c1bv[nt], 0.f);
                s1 += v; s2 += v * v;
            }
            red16_pair(s1, s2);
            if (l16 == 0) { red[wave][mt][quad][r][0] = s1; red[wave][mt][quad][r][1] = s2; }
        }
    __syncthreads();
    if (tid < 50) {
        const int mt = tid >> 4, q = (tid >> 2) & 3, r = tid & 3;
        const float s1 = red[0][mt][q][r][0] + red[1][mt][q][r][0]
                       + red[2][mt][q][r][0] + red[3][mt][q][r][0];
        const float s2 = red[0][mt][q][r][1] + red[1][mt][q][r][1]
                       + red[2][mt][q][r][1] + red[3][mt][q][r][1];
        const float mu  = s1 * (1.f / 256.f);
        const float var = s2 * (1.f / 256.f) - mu * mu;
        fin[tid][0] = mu;
        fin[tid][1] = rsqrtf(var + 1e-5f);
    }
    __syncthreads();

    // ---- write h2 = LN1 rows (h rows l0-1..l0+48; zero outside sequence) ----
#pragma unroll
    for (int mt = 0; mt < 4; ++mt)
#pragma unroll
        for (int r = 0; r < 4; ++r) {
            const int rho = 16 * mt + quad * 4 + r;
            if (rho < 50) {
                const int gr = l0 - 1 + rho;          // global h row
                const float mu = fin[rho][0], rstd = fin[rho][1];
#pragma unroll
                for (int nt = 0; nt < 4; ++nt) {
                    unsigned short hv = 0;
                    if (gr >= 0 && gr < LL) {
                        const float v = fmaxf(acc1[mt][nt][r] + c1bv[nt], 0.f);
                        hv = f2b((v - mu) * rstd * g1v[nt] + b1v[nt]);
                    }
                    sm.h2[rho * PAD + cols[nt]] = hv;
                }
            }
        }

    // ---- conv2: b ring (4 deep), a dbuf (2 deep); b 0,1 pre-barrier ----
    f32x4 acc2[3][4] = {};
    {
        bf16x8 br[4][4], ar2[2][3];
        auto ldb2 = [&](int buf, int s) {
#pragma unroll
            for (int nt = 0; nt < 4; ++nt)
                br[buf][nt] = *reinterpret_cast<const bf16x8*>(
                    wQ2 + (size_t)s * 8192 + cols[nt] * 32 + quad * 8);
        };
        auto lda2 = [&](int buf, int s) {
            const int kc = s >> 3, c8 = s & 7;
#pragma unroll
            for (int mt = 0; mt < 3; ++mt)
                ar2[buf][mt] = *reinterpret_cast<const bf16x8*>(
                    &sm.h2[(16 * mt + l16 + kc) * PAD + c8 * 32 + quad * 8]);
        };
        auto mm2 = [&](int ab, int bb) {
            __builtin_amdgcn_s_setprio(1);
#pragma unroll
            for (int mt = 0; mt < 3; ++mt)
#pragma unroll
                for (int nt = 0; nt < 4; ++nt)
                    acc2[mt][nt] = __builtin_amdgcn_mfma_f32_16x16x32_bf16(
                        ar2[ab][mt], br[bb][nt], acc2[mt][nt], 0, 0, 0);
            __builtin_amdgcn_s_setprio(0);
        };
        ldb2(0, 0);
        ldb2(1, 1);
        __syncthreads();   // h2 ready (b loads retire under the barrier drain)
        lda2(0, 0);
#pragma unroll
        for (int s = 0; s < 24; ++s) {
            if (s + 2 < 24) ldb2((s + 2) & 3, s + 2);
            if (s + 1 < 24) lda2((s + 1) & 1, s + 1);
            mm2(s & 1, s & 3);
        }
    }

    // ---- LN2 stats ----
#pragma unroll
    for (int mt = 0; mt < 3; ++mt)
#pragma unroll
        for (int r = 0; r < 4; ++r) {
            float s1 = 0.f, s2 = 0.f;
#pragma unroll
            for (int nt = 0; nt < 4; ++nt) {
                const float v = fmaxf(acc2[mt][nt][r] + c2bv[nt], 0.f);
                s1 += v; s2 += v * v;
            }
            red16_pair(s1, s2);
            if (l16 == 0) { red[wave][mt][quad][r][0] = s1; red[wave][mt][quad][r][1] = s2; }
        }
    __syncthreads();
    if (tid < MT) {
        const int mt = tid >> 4, q = (tid >> 2) & 3, r = tid & 3;
        const float s1 = red[0][mt][q][r][0] + red[1][mt][q][r][0]
                       + red[2][mt][q][r][0] + red[3][mt][q][r][0];
        const float s2 = red[0][mt][q][r][1] + red[1][mt][q][r][1]
                       + red[2][mt][q][r][1] + red[3][mt][q][r][1];
        const float mu  = s1 * (1.f / 256.f);
        const float var = s2 * (1.f / 256.f) - mu * mu;
        fin[tid][0] = mu;
        fin[tid][1] = rsqrtf(var + 1e-5f);
    }
    __syncthreads();

    // ---- head: dp = sum_col LN2(v)*lw  (direct reference formula) ----
#pragma unroll
    for (int mt = 0; mt < 3; ++mt)
#pragma unroll
        for (int r = 0; r < 4; ++r) {
            const int rho = 16 * mt + quad * 4 + r;
            const float mu = fin[rho][0], rstd = fin[rho][1];
            float p = 0.f;
#pragma unroll
            for (int nt = 0; nt < 4; ++nt) {
                const float v = fmaxf(acc2[mt][nt][r] + c2bv[nt], 0.f);
                p += ((v - mu) * rstd * g2v[nt] + b2v[nt]) * lwv[nt];
            }
            p = red16_one(p);
            if (l16 == 0) redp[wave][mt][quad][r] = p;
        }
    __syncthreads();
    if (tid < MT) {
        const int mt = tid >> 4, q = (tid >> 2) & 3, r = tid & 3;
        const float dp = redp[0][mt][q][r] + redp[1][mt][q][r]
                       + redp[2][mt][q][r] + redp[3][mt][q][r] + lbv;
        out_dur[(size_t)b * LL + l0 + tid] = expf(dp);
    }
}

// ---------------------------------------------------------------------------
// Gather: out[b,t,:] = x[b, idx_map[b][t], :]  (zeros when masked)
// Streaming output (100.7 MB, no reuse) -> nontemporal stores via ext-vector
// f32x4 (native clang vector type).
// ---------------------------------------------------------------------------
__global__ __launch_bounds__(256) void gather_kernel(
    const float* __restrict__ x,       // [B, L, 256]
    const int* __restrict__ idx_map,   // [B, T]
    float* __restrict__ out)           // [B, T, 256]
{
    const int wv = threadIdx.x >> 6, lane = threadIdx.x & 63;
    const int row = blockIdx.x * 4 + wv;          // row in [0, B*T)
    const int b = row / TT, t = row - b * TT;
    const int idx = idx_map[b * TT + t];
    f32x4 val = {0.f, 0.f, 0.f, 0.f};
    if (idx >= 0)
        val = *reinterpret_cast<const f32x4*>(x + ((size_t)(b * LL + idx)) * DD + lane * 4);
    __builtin_nontemporal_store(val, reinterpret_cast<f32x4*>(out) + (size_t)row * (DD / 4) + lane);
}

// ---------------------------------------------------------------------------
extern "C" void kernel_launch(void* const* d_in, const int* in_sizes, int n_in,
                              void* d_out, int out_size, void* d_ws, size_t ws_size,
                              hipStream_t stream)
{
    const float* x      = (const float*)d_in[0];
    const int*   target = (const int*)  d_in[1];
    const float* c1w = (const float*)d_in[3];
    const float* c1b = (const float*)d_in[4];
    const float* g1  = (const float*)d_in[5];
    const float* b1  = (const float*)d_in[6];
    const float* c2w = (const float*)d_in[7];
    const float* c2b = (const float*)d_in[8];
    const float* g2  = (const float*)d_in[9];
    const float* b2  = (const float*)d_in[10];
    const float* lw  = (const float*)d_in[11];
    const float* lb  = (const float*)d_in[12];

    float* out0    = (float*)d_out;                       // [B, T, 256]
    float* out_dpo = out0 + (size_t)BB * TT * DD;         // [B, L]
    float* out_dur = out_dpo + (size_t)BB * LL;           // [B, L]

    // workspace layout
    char* ws = (char*)d_ws;
    unsigned short* wQ1 = (unsigned short*)ws;                 ws += (size_t)24 * 8192 * 2;
    unsigned short* wQ2 = (unsigned short*)ws;                 ws += (size_t)24 * 8192 * 2;
    int* idx_map        = (int*)ws;

    prep_scan_kernel<<<48 + BB, 256, 0, stream>>>(
        c1w, c2w, wQ1, wQ2, target, out_dpo, idx_map);

    fused_dp_kernel<<<BB * (LL / MT), 256, 0, stream>>>(
        x, wQ1, wQ2, c1b, g1, b1, c2b, g2, b2, lw, lb, out_dur);

    gather_kernel<<<BB * TT / 4, 256, 0, stream>>>(x, idx_map, out0);
}

// Round 11
// 193.198 us; speedup vs baseline: 1.0797x; 1.0010x over previous
//
#include <hip/hip_runtime.h>
#include <hip/hip_bf16.h>
#include <math.h>

// Problem constants (fixed by the reference)
#define BB 32
#define LL 768
#define DD 256
#define FF 256
#define TT 3072
#define MT 48              // dp output rows per block -> grid 512 = 2 blocks/CU.
                           // R2-R10: MT=24 (R3), 8-wave (R4), nt=16 (R6), gather-merge
                           // (R8), reg-direct conv1 (R9) regressed; deep ring (R10)
                           // neutral. Geometry is the local optimum; R11 trims the
                           // barrier/phase skeleton instead.
#define PAD 262            // LDS row stride (bf16): dword stride 131 == 3 (mod 32)
#define A1R 66             // A1 rows (memory-safe read range 0..65; rows >=52 zeroed)

typedef __attribute__((ext_vector_type(8))) short bf16x8;
typedef __attribute__((ext_vector_type(4))) float f32x4;

__device__ inline unsigned short f2b(float f) {
    union { float f; unsigned u; } v; v.f = f;
    unsigned r = (v.u + 0x7FFF + ((v.u >> 16) & 1)) >> 16;  // RNE
    return (unsigned short)r;
}

// packed f32x2 -> bf16x2 (RNE), single VALU op
__device__ inline unsigned cvt_pk_bf16(float lo, float hi) {
    unsigned r;
    asm("v_cvt_pk_bf16_f32 %0, %1, %2" : "=v"(r) : "v"(lo), "v"(hi));
    return r;
}

// ---------------------------------------------------------------------------
// 16-lane-group sum via DPP row rotations (verified R2: bank conflicts = 0).
// ---------------------------------------------------------------------------
#define DPP_ROR_ADD(v, ctrl)                                                   \
    v += __int_as_float(__builtin_amdgcn_update_dpp(                           \
        0, __float_as_int(v), ctrl, 0xF, 0xF, false))

__device__ inline void red16_pair(float& a, float& b) {
    DPP_ROR_ADD(a, 0x128); DPP_ROR_ADD(b, 0x128);   // ror:8
    DPP_ROR_ADD(a, 0x124); DPP_ROR_ADD(b, 0x124);   // ror:4
    DPP_ROR_ADD(a, 0x122); DPP_ROR_ADD(b, 0x122);   // ror:2
    DPP_ROR_ADD(a, 0x121); DPP_ROR_ADD(b, 0x121);   // ror:1
}

__device__ inline void red16_tri(float& a, float& b, float& c) {
    DPP_ROR_ADD(a, 0x128); DPP_ROR_ADD(b, 0x128); DPP_ROR_ADD(c, 0x128);
    DPP_ROR_ADD(a, 0x124); DPP_ROR_ADD(b, 0x124); DPP_ROR_ADD(c, 0x124);
    DPP_ROR_ADD(a, 0x122); DPP_ROR_ADD(b, 0x122); DPP_ROR_ADD(c, 0x122);
    DPP_ROR_ADD(a, 0x121); DPP_ROR_ADD(b, 0x121); DPP_ROR_ADD(c, 0x121);
}

// ---------------------------------------------------------------------------
// MERGED: weight prep (blocks 0..47) + scan/dpo/idx_map (blocks 48..79).
// R11: scan uses a wave shfl_up prefix + single cross-wave fixup barrier
// (was 16-barrier Hillis-Steele) -- scan is on fused_dp's critical path.
//   wQ[s*8192 + n*32 + q*8 + j] = bf16(w[kc][c8*32+q*8+j][n]),  s = kc*8+c8
// ---------------------------------------------------------------------------
__global__ __launch_bounds__(256) void prep_scan_kernel(
    const float* __restrict__ w1, const float* __restrict__ w2,
    unsigned short* __restrict__ wQ1, unsigned short* __restrict__ wQ2,
    const int* __restrict__ target,    // [B, L]
    float* __restrict__ out_dpo,       // [B, L] (stored as float)
    int* __restrict__ idx_map)         // [B, T]
{
    __shared__ int wsum[4];
    const int tid = threadIdx.x;

    if (blockIdx.x < 48) {
        // ---------------- weight prep ----------------
        const int layer = blockIdx.x / 24;
        const int s  = blockIdx.x % 24;
        const int kc = s >> 3, c8 = s & 7;
        const float* __restrict__ w = layer ? w2 : w1;
        unsigned short* __restrict__ o = (layer ? wQ2 : wQ1) + s * 8192 + tid * 32;
        const int n = tid;

        alignas(16) unsigned short tmp[32];
#pragma unroll
        for (int q = 0; q < 4; ++q)
#pragma unroll
            for (int j = 0; j < 8; ++j) {
                const int cin = c8 * 32 + q * 8 + j;
                tmp[q * 8 + j] = f2b(w[((size_t)(kc * 256 + cin)) * 256 + n]);
            }
#pragma unroll
        for (int i = 0; i < 4; ++i)
            *reinterpret_cast<uint4*>(o + i * 8) = *reinterpret_cast<const uint4*>(tmp + i * 8);
        return;
    }

    // ---------------- scan: dpo + cumsum + scatter idx map ----------------
    const int b  = blockIdx.x - 48;
    const int wv = tid >> 6, lane = tid & 63;

    const int l = 3 * tid;
    const int v0 = target[b * LL + l];
    const int v1 = target[b * LL + l + 1];
    const int v2 = target[b * LL + l + 2];
    out_dpo[b * LL + l]     = (float)v0;
    out_dpo[b * LL + l + 1] = (float)v1;
    out_dpo[b * LL + l + 2] = (float)v2;

    const int s0 = v0, s1 = v0 + v1, s2 = v0 + v1 + v2;

    // wave-level inclusive scan of s2 (6 shfl_up steps), then cross-wave fixup
    int inc = s2;
#pragma unroll
    for (int off = 1; off < 64; off <<= 1) {
        const int t = __shfl_up(inc, off, 64);
        if (lane >= off) inc += t;
    }
    if (lane == 63) wsum[wv] = inc;

    // idx_map default fill overlaps the scan barrier
    for (int t = tid; t < TT; t += 256) idx_map[b * TT + t] = -1;
    __syncthreads();

    int woff = 0;
#pragma unroll
    for (int w = 0; w < 4; ++w) woff += (w < wv) ? wsum[w] : 0;
    const int excl = woff + inc - s2;

    const int c0 = excl + s0, c1 = excl + s1, c2 = excl + s2;
    for (int t = excl; t < c0 && t < TT; ++t) idx_map[b * TT + t] = l;
    for (int t = c0;   t < c1 && t < TT; ++t) idx_map[b * TT + t] = l + 1;
    for (int t = c1;   t < c2 && t < TT; ++t) idx_map[b * TT + t] = l + 2;
}

// ---------------------------------------------------------------------------
// FUSED DurationPredictor — R10 pipeline + R11 skeleton trim:
//  * redundant "A1 dead" barrier removed (red1+fin1 syncs already order
//    all A1 reads before any h2 write)
//  * head folded into LN2 reduction: dp = rstd*(svgl - mu*SGL) + SBL + lb,
//    svgl reduced as 3rd DPP chain; SGL/SBL are column constants reduced
//    once at entry.  Deletes fin2 + head phases and 2 barriers.
//  Barriers: 8 -> 5 (stage, red1, fin1, h2-ready, red2).
// ---------------------------------------------------------------------------
__global__ __launch_bounds__(256, 2) void fused_dp_kernel(
    const float* __restrict__ x,               // [B, L, 256] fp32
    const unsigned short* __restrict__ wQ1,    // fragment-major conv1 weights
    const unsigned short* __restrict__ wQ2,    // fragment-major conv2 weights
    const float* __restrict__ c1b, const float* __restrict__ g1, const float* __restrict__ b1,
    const float* __restrict__ c2b, const float* __restrict__ g2, const float* __restrict__ b2,
    const float* __restrict__ lw,  const float* __restrict__ lb,
    float* __restrict__ out_dur)               // [B, L]
{
    __shared__ union {
        unsigned short A1[A1R * PAD];          // 34.6 KB staged x rows (bf16)
        unsigned short h2[50 * PAD];           // 26.2 KB LN'd conv1 rows (bf16)
    } sm;
    __shared__ float red[4][4][4][4][3];       // [wave][mt][quad][r][{s1,s2,svgl}]
    __shared__ float fin[50][2];               // per-row (mu, rstd) for LN1
    __shared__ float cst[4][2];                // per-wave {SGL, SBL} partials

    const int tid  = threadIdx.x;
    const int b    = blockIdx.x / (LL / MT);
    const int l0   = (blockIdx.x % (LL / MT)) * MT;
    const int wave = tid >> 6, lane = tid & 63;
    const int quad = lane >> 4, l16 = lane & 15;

    // ---- hoist per-lane column constants ----
    int   cols[4];
    float c1bv[4], g1v[4], b1v[4], c2bv[4], g2v[4], b2v[4], lwv[4];
#pragma unroll
    for (int nt = 0; nt < 4; ++nt) {
        const int c = wave * 64 + nt * 16 + l16;
        cols[nt] = c;
        c1bv[nt] = c1b[c]; g1v[nt] = g1[c]; b1v[nt] = b1[c];
        c2bv[nt] = c2b[c]; g2v[nt] = g2[c]; b2v[nt] = b2[c];
        lwv[nt]  = lw[c];
    }
    const float lbv = lb[0];

    // ---- per-wave head constants: SGL = sum g2*lw, SBL = sum b2*lw over the
    //      wave's 64 cols (quad-independent; lane 0 writes).  Ordered before
    //      final use by every later barrier. ----
    {
        float sgl = 0.f, sbl = 0.f;
#pragma unroll
        for (int nt = 0; nt < 4; ++nt) {
            sgl += g2v[nt] * lwv[nt];
            sbl += b2v[nt] * lwv[nt];
        }
        red16_pair(sgl, sbl);
        if (lane == 0) { cst[wave][0] = sgl; cst[wave][1] = sbl; }
    }

    // ---- stage x rows l0-2 .. l0+49 (rows 52..65 zeroed), BATCHED loads ----
    {
        float4 v0[7], v1[7];
        int lr[7];
#pragma unroll
        for (int k = 0; k < 7; ++k) {
            const int q  = tid + (k << 8);
            const int ar = q >> 5;
            const int l  = l0 - 2 + ar;
            lr[k] = (ar < 52 && l >= 0 && l < LL) ? l : -1;
            if (lr[k] >= 0) {
                const float* pp = x + ((size_t)b * LL + lr[k]) * DD + (q & 31) * 8;
                v0[k] = *reinterpret_cast<const float4*>(pp);
                v1[k] = *reinterpret_cast<const float4*>(pp + 4);
            }
        }
#pragma unroll
        for (int k = 0; k < 7; ++k) {
            const int q  = tid + (k << 8);
            const int ar = q >> 5;
            uint4 uu = {0u, 0u, 0u, 0u};
            if (lr[k] >= 0) {
                uu.x = cvt_pk_bf16(v0[k].x, v0[k].y);
                uu.y = cvt_pk_bf16(v0[k].z, v0[k].w);
                uu.z = cvt_pk_bf16(v1[k].x, v1[k].y);
                uu.w = cvt_pk_bf16(v1[k].z, v1[k].w);
            }
            *reinterpret_cast<uint4*>(&sm.A1[ar * PAD + (q & 31) * 8]) = uu;
        }
        for (int q = tid; q < 320; q += 256) {
            const int ar = 56 + (q >> 5);
            uint4 z = {0u, 0u, 0u, 0u};
            *reinterpret_cast<uint4*>(&sm.A1[ar * PAD + (q & 31) * 8]) = z;
        }
    }

    // ---- conv1: b ring (4 deep), a dbuf (2 deep) ----
    f32x4 acc1[4][4] = {};
    {
        bf16x8 br[4][4], ar2[2][4];
        auto ldb1 = [&](int buf, int s) {
#pragma unroll
            for (int nt = 0; nt < 4; ++nt)
                br[buf][nt] = *reinterpret_cast<const bf16x8*>(
                    wQ1 + (size_t)s * 8192 + cols[nt] * 32 + quad * 8);
        };
        auto lda1 = [&](int buf, int s) {
            const int kc = s >> 3, c8 = s & 7;
#pragma unroll
            for (int mt = 0; mt < 4; ++mt)
                ar2[buf][mt] = *reinterpret_cast<const bf16x8*>(
                    &sm.A1[(16 * mt + l16 + kc) * PAD + c8 * 32 + quad * 8]);
        };
        auto mm1 = [&](int ab, int bb) {
            __builtin_amdgcn_s_setprio(1);
#pragma unroll
            for (int mt = 0; mt < 4; ++mt)
#pragma unroll
                for (int nt = 0; nt < 4; ++nt)
                    acc1[mt][nt] = __builtin_amdgcn_mfma_f32_16x16x32_bf16(
                        ar2[ab][mt], br[bb][nt], acc1[mt][nt], 0, 0, 0);
            __builtin_amdgcn_s_setprio(0);
        };
        // b steps 0,1 issued pre-barrier: barrier's vmcnt drain retires them free
        ldb1(0, 0);
        ldb1(1, 1);
        __syncthreads();   // A1 ready
        lda1(0, 0);
#pragma unroll
        for (int s = 0; s < 24; ++s) {
            if (s + 2 < 24) ldb1((s + 2) & 3, s + 2);   // b 2 ahead
            if (s + 1 < 24) lda1((s + 1) & 1, s + 1);   // a 1 ahead
            mm1(s & 1, s & 3);
        }
    }
    // NOTE: no barrier here.  A1 reads all precede each wave's red write; h2
    // writes happen only after the red1 AND fin1 barriers below -> safe.

    // ---- LN1 stats: register-direct quad-group DPP reduction ----
#pragma unroll
    for (int mt = 0; mt < 4; ++mt)
#pragma unroll
        for (int r = 0; r < 4; ++r) {
            float s1 = 0.f, s2 = 0.f;
#pragma unroll
            for (int nt = 0; nt < 4; ++nt) {
                const float v = fmaxf(acc1[mt][nt][r] + c1bv[nt], 0.f);
                s1 += v; s2 += v * v;
            }
            red16_pair(s1, s2);
            if (l16 == 0) { red[wave][mt][quad][r][0] = s1; red[wave][mt][quad][r][1] = s2; }
        }
    __syncthreads();   // red1
    if (tid < 50) {
        const int mt = tid >> 4, q = (tid >> 2) & 3, r = tid & 3;
        const float s1 = red[0][mt][q][r][0] + red[1][mt][q][r][0]
                       + red[2][mt][q][r][0] + red[3][mt][q][r][0];
        const float s2 = red[0][mt][q][r][1] + red[1][mt][q][r][1]
                       + red[2][mt][q][r][1] + red[3][mt][q][r][1];
        const float mu  = s1 * (1.f / 256.f);
        const float var = s2 * (1.f / 256.f) - mu * mu;
        fin[tid][0] = mu;
        fin[tid][1] = rsqrtf(var + 1e-5f);
    }
    __syncthreads();   // fin1

    // ---- write h2 = LN1 rows (h rows l0-1..l0+48; zero outside sequence) ----
#pragma unroll
    for (int mt = 0; mt < 4; ++mt)
#pragma unroll
        for (int r = 0; r < 4; ++r) {
            const int rho = 16 * mt + quad * 4 + r;
            if (rho < 50) {
                const int gr = l0 - 1 + rho;          // global h row
                const float mu = fin[rho][0], rstd = fin[rho][1];
#pragma unroll
                for (int nt = 0; nt < 4; ++nt) {
                    unsigned short hv = 0;
                    if (gr >= 0 && gr < LL) {
                        const float v = fmaxf(acc1[mt][nt][r] + c1bv[nt], 0.f);
                        hv = f2b((v - mu) * rstd * g1v[nt] + b1v[nt]);
                    }
                    sm.h2[rho * PAD + cols[nt]] = hv;
                }
            }
        }

    // ---- conv2: b ring (4 deep), a dbuf (2 deep); b 0,1 pre-barrier ----
    f32x4 acc2[3][4] = {};
    {
        bf16x8 br[4][4], ar2[2][3];
        auto ldb2 = [&](int buf, int s) {
#pragma unroll
            for (int nt = 0; nt < 4; ++nt)
                br[buf][nt] = *reinterpret_cast<const bf16x8*>(
                    wQ2 + (size_t)s * 8192 + cols[nt] * 32 + quad * 8);
        };
        auto lda2 = [&](int buf, int s) {
            const int kc = s >> 3, c8 = s & 7;
#pragma unroll
            for (int mt = 0; mt < 3; ++mt)
                ar2[buf][mt] = *reinterpret_cast<const bf16x8*>(
                    &sm.h2[(16 * mt + l16 + kc) * PAD + c8 * 32 + quad * 8]);
        };
        auto mm2 = [&](int ab, int bb) {
            __builtin_amdgcn_s_setprio(1);
#pragma unroll
            for (int mt = 0; mt < 3; ++mt)
#pragma unroll
                for (int nt = 0; nt < 4; ++nt)
                    acc2[mt][nt] = __builtin_amdgcn_mfma_f32_16x16x32_bf16(
                        ar2[ab][mt], br[bb][nt], acc2[mt][nt], 0, 0, 0);
            __builtin_amdgcn_s_setprio(0);
        };
        ldb2(0, 0);
        ldb2(1, 1);
        __syncthreads();   // h2 ready (b loads retire under the barrier drain)
        lda2(0, 0);
#pragma unroll
        for (int s = 0; s < 24; ++s) {
            if (s + 2 < 24) ldb2((s + 2) & 3, s + 2);
            if (s + 1 < 24) lda2((s + 1) & 1, s + 1);
            mm2(s & 1, s & 3);
        }
    }

    // ---- LN2 stats + head partial svgl in ONE 3-chain DPP reduction ----
#pragma unroll
    for (int mt = 0; mt < 3; ++mt)
#pragma unroll
        for (int r = 0; r < 4; ++r) {
            float s1 = 0.f, s2 = 0.f, svgl = 0.f;
#pragma unroll
            for (int nt = 0; nt < 4; ++nt) {
                const float v = fmaxf(acc2[mt][nt][r] + c2bv[nt], 0.f);
                s1 += v; s2 += v * v; svgl += v * g2v[nt] * lwv[nt];
            }
            red16_tri(s1, s2, svgl);
            if (l16 == 0) {
                red[wave][mt][quad][r][0] = s1;
                red[wave][mt][quad][r][1] = s2;
                red[wave][mt][quad][r][2] = svgl;
            }
        }
    __syncthreads();   // red2

    // ---- final: dp = rstd*(svgl - mu*SGL) + SBL + lb, direct store ----
    if (tid < MT) {
        const int mt = tid >> 4, q = (tid >> 2) & 3, r = tid & 3;
        float s1 = 0.f, s2 = 0.f, svgl = 0.f, SGL = 0.f, SBL = 0.f;
#pragma unroll
        for (int w = 0; w < 4; ++w) {
            s1   += red[w][mt][q][r][0];
            s2   += red[w][mt][q][r][1];
            svgl += red[w][mt][q][r][2];
            SGL  += cst[w][0];
            SBL  += cst[w][1];
        }
        const float mu   = s1 * (1.f / 256.f);
        const float var  = s2 * (1.f / 256.f) - mu * mu;
        const float rstd = rsqrtf(var + 1e-5f);
        const float dp   = rstd * (svgl - mu * SGL) + SBL + lbv;
        out_dur[(size_t)b * LL + l0 + tid] = expf(dp);
    }
}

// ---------------------------------------------------------------------------
// Gather: out[b,t,:] = x[b, idx_map[b][t], :]  (zeros when masked)
// Streaming output (100.7 MB, no reuse) -> nontemporal stores via ext-vector
// f32x4 (native clang vector type).
// ---------------------------------------------------------------------------
__global__ __launch_bounds__(256) void gather_kernel(
    const float* __restrict__ x,       // [B, L, 256]
    const int* __restrict__ idx_map,   // [B, T]
    float* __restrict__ out)           // [B, T, 256]
{
    const int wv = threadIdx.x >> 6, lane = threadIdx.x & 63;
    const int row = blockIdx.x * 4 + wv;          // row in [0, B*T)
    const int b = row / TT, t = row - b * TT;
    const int idx = idx_map[b * TT + t];
    f32x4 val = {0.f, 0.f, 0.f, 0.f};
    if (idx >= 0)
        val = *reinterpret_cast<const f32x4*>(x + ((size_t)(b * LL + idx)) * DD + lane * 4);
    __builtin_nontemporal_store(val, reinterpret_cast<f32x4*>(out) + (size_t)row * (DD / 4) + lane);
}

// ---------------------------------------------------------------------------
extern "C" void kernel_launch(void* const* d_in, const int* in_sizes, int n_in,
                              void* d_out, int out_size, void* d_ws, size_t ws_size,
                              hipStream_t stream)
{
    const float* x      = (const float*)d_in[0];
    const int*   target = (const int*)  d_in[1];
    const float* c1w = (const float*)d_in[3];
    const float* c1b = (const float*)d_in[4];
    const float* g1  = (const float*)d_in[5];
    const float* b1  = (const float*)d_in[6];
    const float* c2w = (const float*)d_in[7];
    const float* c2b = (const float*)d_in[8];
    const float* g2  = (const float*)d_in[9];
    const float* b2  = (const float*)d_in[10];
    const float* lw  = (const float*)d_in[11];
    const float* lb  = (const float*)d_in[12];

    float* out0    = (float*)d_out;                       // [B, T, 256]
    float* out_dpo = out0 + (size_t)BB * TT * DD;         // [B, L]
    float* out_dur = out_dpo + (size_t)BB * LL;           // [B, L]

    // workspace layout
    char* ws = (char*)d_ws;
    unsigned short* wQ1 = (unsigned short*)ws;                 ws += (size_t)24 * 8192 * 2;
    unsigned short* wQ2 = (unsigned short*)ws;                 ws += (size_t)24 * 8192 * 2;
    int* idx_map        = (int*)ws;

    prep_scan_kernel<<<48 + BB, 256, 0, stream>>>(
        c1w, c2w, wQ1, wQ2, target, out_dpo, idx_map);

    fused_dp_kernel<<<BB * (LL / MT), 256, 0, stream>>>(
        x, wQ1, wQ2, c1b, g1, b1, c2b, g2, b2, lw, lb, out_dur);

    gather_kernel<<<BB * TT / 4, 256, 0, stream>>>(x, idx_map, out0);
}